// Round 3
// baseline (2743.069 us; speedup 1.0000x reference)
//
#include <hip/hip_runtime.h>
#include <cmath>

// Problem constants
#define B_ 1024
#define V_ 8192
#define E_ 64
#define H_ 64
#define L_ 16
#define SOS 1
#define EOS 2

typedef float f32x4 __attribute__((ext_vector_type(4)));

// d_out layout (floats), in reference return order:
// output [B,17,V] | seq_lengths [B] | entropy [1] | hidden_state [B,H] | embeds [B,L,E]
#define ONEHOT_OFF 0ull
#define SEQ_OFF    142606336ull
#define ENT_OFF    142607360ull
#define HID_OFF    142607361ull
#define EMB_OFF    142672897ull

__global__ __launch_bounds__(64) void ent_init_kernel(float* __restrict__ out)
{
    if (threadIdx.x == 0) out[ENT_OFF] = 0.f;
}

// ---------------------------------------------------------------------------
// Communication-free fused kernel. Grid: 256 blocks x 512 threads (1/CU).
// Block b owns rows 4b..4b+3 for the entire 16-step recurrence. Per step:
// 32 double-buffered 256-v chunks of W_out staged LDS <- XCD-L2 (2 MB/step),
// logits GEMM + online-softmax stats + argmax(l+g); wave butterfly + 4-wave
// LDS combine -> token/entropy/seq (threads 0..3 own rows); emb gather;
// gates GEMM direct from L2 (128 KB/step, L1-resident window); LSTM pointwise
// (c in registers of threads 0..255). No inter-block sync anywhere.
// Exact-math paths (dot-product order, epilogue, comparator, LSTM) are
// textually identical to the R1-passing kernel -> tokens/one-hot/seq exact.
// ---------------------------------------------------------------------------
__global__ __launch_bounds__(512, 1) void fused_rows_kernel(
    const float* __restrict__ emb_table,
    const float* __restrict__ W_ih, const float* __restrict__ W_hh,
    const float* __restrict__ b_ih, const float* __restrict__ b_hh,
    const float* __restrict__ hidden_in,
    const float* __restrict__ Wout, const float* __restrict__ bout,
    const float* __restrict__ gumbels,
    float* __restrict__ out)
{
    __shared__ float wV[2][256][68];   // W_out chunk, pad 68: lanes=consecutive v -> conflict-free
    __shared__ float X[4][132];        // [row][emb 0..63 | h 64..127]
    __shared__ float gatesL[4][256];
    __shared__ float red[8][2][8];     // [wave][row-in-pair][m,S,T,bv,bi]
    __shared__ int   tokL[4];
    __shared__ float entS[4];

    const int t  = threadIdx.x;
    const int rowBase = blockIdx.x * 4;
    const int lane = t & 63;
    const int wid  = t >> 6;          // wave 0..7
    const int rp   = t >> 8;          // row-pair 0..1
    const int vl   = t & 255;         // v within chunk
    const int r0   = rp * 2;          // local rows r0, r0+1

    float c_reg = 0.f;                // t<256: cell state for (row=t>>6, uu=t&63)
    float ent_acc = 0.f;              // t<4: entropy accumulator for row t
    int   sl = L_ + 1;                // t<4: seq length for row t

    // ---- prologue: zero one-hot slab 0 (+SOS at v=1), stage X = [emb(SOS)|h0]
#pragma unroll
    for (int q = 0; q < 16; ++q) {
        const int n = q * 512 + t;        // f4 index over 4 rows x 32KB
        const int r = n >> 11;
        const int v4 = n & 2047;
        f32x4 z = {0.f, 0.f, 0.f, 0.f};
        if (v4 == 0) z.y = 1.0f;          // v=1 == SOS
        __builtin_nontemporal_store(z,
            (f32x4*)(out + (size_t)(rowBase + r) * (17 * 8192) + (size_t)v4 * 4));
    }
    if (t < 256) {
        const int r = t >> 6, k = t & 63;
        const float ev = emb_table[(size_t)SOS * 64 + k];
        X[r][k] = ev;
        out[EMB_OFF + ((size_t)(rowBase + r) * 16) * 64 + k] = ev;
    } else {
        const int r = (t - 256) >> 6, k = t & 63;
        X[r][64 + k] = hidden_in[(size_t)(rowBase + r) * 64 + k];
    }
    __syncthreads();

    // gates GEMM (W direct from L2, L1-resident window) + LSTM pointwise.
    // Exact order mirror of R1: bias, then ih k=0..63, then hh k=0..63.
    auto gates_lstm = [&]() {
        {
            const int u = vl;                       // gate-row 0..255 (i,f,g,o blocks)
            const float bia = b_ih[u] + b_hh[u];
            float acc0 = bia, acc1 = bia;
            const float* wih = W_ih + (size_t)u * 64;
            const float* whh = W_hh + (size_t)u * 64;
            for (int k4 = 0; k4 < 16; ++k4) {
                const float4 w4 = *(const float4*)(wih + k4 * 4);
                const float4 x0 = *(const float4*)&X[r0][k4 * 4];
                const float4 x1 = *(const float4*)&X[r0 + 1][k4 * 4];
                acc0 += x0.x * w4.x + x0.y * w4.y + x0.z * w4.z + x0.w * w4.w;
                acc1 += x1.x * w4.x + x1.y * w4.y + x1.z * w4.z + x1.w * w4.w;
            }
            for (int k4 = 0; k4 < 16; ++k4) {
                const float4 w4 = *(const float4*)(whh + k4 * 4);
                const float4 x0 = *(const float4*)&X[r0][64 + k4 * 4];
                const float4 x1 = *(const float4*)&X[r0 + 1][64 + k4 * 4];
                acc0 += x0.x * w4.x + x0.y * w4.y + x0.z * w4.z + x0.w * w4.w;
                acc1 += x1.x * w4.x + x1.y * w4.y + x1.z * w4.z + x1.w * w4.w;
            }
            gatesL[r0][u] = acc0;
            gatesL[r0 + 1][u] = acc1;
        }
        __syncthreads();
        if (t < 256) {
            const int row = t >> 6, uu = t & 63;
            const float ii = gatesL[row][uu];
            const float ff = gatesL[row][64 + uu];
            const float gg = gatesL[row][128 + uu];
            const float oo = gatesL[row][192 + uu];
            const float si = 1.f / (1.f + expf(-ii));
            const float sf = 1.f / (1.f + expf(-ff));
            const float so = 1.f / (1.f + expf(-oo));
            const float cn = sf * c_reg + si * tanhf(gg);
            const float hn = so * tanhf(cn);
            c_reg = cn;
            X[row][64 + uu] = hn;
        }
        __syncthreads();
    };

    gates_lstm();    // h(0)

    // ---------------- main loop ------------------------------------------------
    for (int i = 0; i < 16; ++i) {
        const float* gstep = gumbels + (size_t)i * 8388608ull;   // i*B*V

        float m[2], S[2], T[2], bv[2];
        int   bi[2];
#pragma unroll
        for (int r = 0; r < 2; ++r) {
            m[r] = -INFINITY; S[r] = 0.f; T[r] = 0.f; bv[r] = -INFINITY; bi[r] = 0;
        }

        // preload chunk 0 (stage + gumbel/bias regs)
#pragma unroll
        for (int q = 0; q < 8; ++q) {
            const int n = q * 512 + t;
            const int svl = n >> 4, sk = (n & 15) * 4;
            *(float4*)&wV[0][svl][sk] =
                *(const float4*)(Wout + ((size_t)svl * 64 + sk));
        }
        float g0 = __builtin_nontemporal_load(gstep + (size_t)(rowBase + r0) * V_ + vl);
        float g1 = __builtin_nontemporal_load(gstep + (size_t)(rowBase + r0 + 1) * V_ + vl);
        float bo = bout[vl];
        __syncthreads();

        for (int c = 0; c < 32; ++c) {
            const int buf = c & 1;
            float gn0 = 0.f, gn1 = 0.f, bn = 0.f;
            if (c < 31) {
                const int vn = (c + 1) * 256 + vl;
                gn0 = __builtin_nontemporal_load(gstep + (size_t)(rowBase + r0) * V_ + vn);
                gn1 = __builtin_nontemporal_load(gstep + (size_t)(rowBase + r0 + 1) * V_ + vn);
                bn = bout[vn];
#pragma unroll
                for (int q = 0; q < 8; ++q) {
                    const int n = q * 512 + t;
                    const int svl = n >> 4, sk = (n & 15) * 4;
                    *(float4*)&wV[buf ^ 1][svl][sk] =
                        *(const float4*)(Wout + ((size_t)((c + 1) * 256 + svl) * 64 + sk));
                }
            }
            if (c < 16) {     // fused zero-fill of one-hot slab i+1 (4 rows x 32KB)
                const int n = c * 512 + t;
                const int r = n >> 11, v4 = n & 2047;
                const f32x4 z = {0.f, 0.f, 0.f, 0.f};
                __builtin_nontemporal_store(z,
                    (f32x4*)(out + (size_t)(rowBase + r) * (17 * 8192)
                                 + (size_t)(i + 1) * 8192 + (size_t)v4 * 4));
            }

            float acc0 = 0.f, acc1 = 0.f;
#pragma unroll
            for (int k4 = 0; k4 < 16; ++k4) {
                const float4 wv4 = *(const float4*)&wV[buf][vl][k4 * 4];
                const float4 h0 = *(const float4*)&X[r0][64 + k4 * 4];
                const float4 h1 = *(const float4*)&X[r0 + 1][64 + k4 * 4];
                acc0 += h0.x * wv4.x + h0.y * wv4.y + h0.z * wv4.z + h0.w * wv4.w;
                acc1 += h1.x * wv4.x + h1.y * wv4.y + h1.z * wv4.z + h1.w * wv4.w;
            }

            const int v = c * 256 + vl;
            {
                const float l = acc0 + bo;
                const float s = l + g0;
                if (s > bv[0]) { bv[0] = s; bi[0] = v; }   // strict > keeps lowest v
                const float mn = fmaxf(m[0], l);
                const float e  = __expf(-fabsf(l - m[0])); // exp(-inf)=0 first time
                const bool nw  = l > m[0];
                const float a  = nw ? e : 1.f;
                const float b2 = nw ? 1.f : e;
                S[0] = S[0] * a + b2;
                T[0] = T[0] * a + l * b2;
                m[0] = mn;
            }
            {
                const float l = acc1 + bo;
                const float s = l + g1;
                if (s > bv[1]) { bv[1] = s; bi[1] = v; }
                const float mn = fmaxf(m[1], l);
                const float e  = __expf(-fabsf(l - m[1]));
                const bool nw  = l > m[1];
                const float a  = nw ? e : 1.f;
                const float b2 = nw ? 1.f : e;
                S[1] = S[1] * a + b2;
                T[1] = T[1] * a + l * b2;
                m[1] = mn;
            }
            g0 = gn0; g1 = gn1; bo = bn;
            __syncthreads();
        }

        // wave-64 butterfly (each wave holds 2 rows over its vl-range)
#pragma unroll
        for (int off = 1; off < 64; off <<= 1) {
#pragma unroll
            for (int r = 0; r < 2; ++r) {
                const float mo  = __shfl_xor(m[r], off);
                const float So  = __shfl_xor(S[r], off);
                const float To  = __shfl_xor(T[r], off);
                const float bvo = __shfl_xor(bv[r], off);
                const int   bio = __shfl_xor(bi[r], off);
                const float mn = fmaxf(m[r], mo);
                const float ea = __expf(m[r] - mn);
                const float eb = __expf(mo - mn);
                S[r] = S[r] * ea + So * eb;
                T[r] = T[r] * ea + To * eb;
                m[r] = mn;
                if (bvo > bv[r] || (bvo == bv[r] && bio < bi[r])) { bv[r] = bvo; bi[r] = bio; }
            }
        }
        if (lane == 0) {
#pragma unroll
            for (int r = 0; r < 2; ++r) {
                red[wid][r][0] = m[r];  red[wid][r][1] = S[r]; red[wid][r][2] = T[r];
                red[wid][r][3] = bv[r]; red[wid][r][4] = __int_as_float(bi[r]);
            }
        }
        __syncthreads();

        // final combine: thread r (0..3) owns row rowBase+r (waves 4*(r>>1)..+3)
        if (t < 4) {
            const int row = rowBase + t;
            const int rpp = t >> 1, rr = t & 1;
            float m2 = -INFINITY, S2 = 0.f, T2 = 0.f, bv2 = -INFINITY; int bi2 = 0;
            for (int ww = 0; ww < 4; ++ww) {
                const int idx = rpp * 4 + ww;
                const float ms = red[idx][rr][0], Ss = red[idx][rr][1], Ts = red[idx][rr][2];
                const float bvs = red[idx][rr][3];
                const int   bis = __float_as_int(red[idx][rr][4]);
                const float mn = fmaxf(m2, ms);
                const float ea = __expf(m2 - mn), eb = __expf(ms - mn);
                S2 = S2 * ea + Ss * eb; T2 = T2 * ea + Ts * eb; m2 = mn;
                if (bvs > bv2 || (bvs == bv2 && bis < bi2)) { bv2 = bvs; bi2 = bis; }
            }
            const float lse  = m2 + logf(S2);
            const float entc = lse - T2 / S2;
            const int tok = bi2;
            out[ONEHOT_OFF + (size_t)row * (17 * 8192) + (size_t)(i + 1) * 8192 + tok] = 1.0f;
            ent_acc += entc;
            if (tok == EOS && sl == (L_ + 1)) sl = i + 2;   // (max_pred==1.0 always)
            tokL[t] = tok;
            if (i == 15) { out[SEQ_OFF + row] = (float)sl; entS[t] = ent_acc; }
        }
        __syncthreads();

        if (i == 15) break;

        // emb gather for token(i) -> X emb-half + embeds output
        if (t < 256) {
            const int r = t >> 6, k = t & 63;
            const int tk = tokL[r];
            const float ev = emb_table[(size_t)tk * 64 + k];
            X[r][k] = ev;
            out[EMB_OFF + ((size_t)(rowBase + r) * 16 + (size_t)(i + 1)) * 64 + k] = ev;
        }
        __syncthreads();

        gates_lstm();   // h(i+1)
    }

    if (t == 0) {
        const float a = entS[0] + entS[1] + entS[2] + entS[3];
        atomicAdd(out + ENT_OFF, a * (1.0f / (1024.0f * 16.0f)));
    }
}

extern "C" void kernel_launch(void* const* d_in, const int* in_sizes, int n_in,
                              void* d_out, int out_size, void* d_ws, size_t ws_size,
                              hipStream_t stream) {
    (void)in_sizes; (void)ws_size; (void)out_size; (void)d_ws;
    if (n_in < 9) return;
    const float* hidden    = (const float*)d_in[0];
    const float* embedding = (const float*)d_in[1];
    const float* W_ih      = (const float*)d_in[2];
    const float* W_hh      = (const float*)d_in[3];
    const float* b_ih      = (const float*)d_in[4];
    const float* b_hh      = (const float*)d_in[5];
    const float* W_out     = (const float*)d_in[6];
    const float* b_out     = (const float*)d_in[7];
    const float* gumbels   = (const float*)d_in[8];
    float* out = (float*)d_out;

    (void)hipMemcpyAsync(out + HID_OFF, hidden, (size_t)B_ * H_ * sizeof(float),
                         hipMemcpyDeviceToDevice, stream);
    ent_init_kernel<<<1, 64, 0, stream>>>(out);
    fused_rows_kernel<<<256, 512, 0, stream>>>(embedding, W_ih, W_hh, b_ih, b_hh,
        hidden, W_out, b_out, gumbels, out);
}

// Round 4
// 1622.193 us; speedup vs baseline: 1.6910x; 1.6910x over previous
//
#include <hip/hip_runtime.h>
#include <cmath>

// Problem constants
#define B_ 1024
#define V_ 8192
#define E_ 64
#define H_ 64
#define L_ 16
#define SOS 1
#define EOS 2

typedef float f32x4 __attribute__((ext_vector_type(4)));

// d_out layout (floats), in reference return order:
// output [B,17,V] | seq_lengths [B] | entropy [1] | hidden_state [B,H] | embeds [B,L,E]
#define ONEHOT_OFF 0ull
#define SEQ_OFF    142606336ull
#define ENT_OFF    142607360ull
#define HID_OFF    142607361ull
#define EMB_OFF    142672897ull

// ---------------------------------------------------------------------------
// One dispatch per step. Grid 512 = 64 row-groups (rg, 16 rows) x 8 v-splits
// (vs, 1024 v); 2 blocks/CU. Dispatch i (step=i):
//   prologue (redundant per block, cross-dispatch inputs => safe by stream
//   order): combine step i-1 partials -> token/entc (+ one-hot 1.0, vs==0),
//   emb gather, gates GEMM (16 rows x 256 units, W direct from L2), LSTM ->
//   h(i) in LDS. Then R1-proven logits slice: 4x 256-v chunks of W_out staged
//   to LDS, GEMM + online-softmax stats + argmax(l+g), butterfly, partials.
// Cross-dispatch state is parity double-buffered (partials, h, c) to avoid
// same-dispatch read/write races; ent/seq are per-step write-once slots,
// reconstructed at the final dispatch in identical summation order.
// step==16 (grid 64): combine(15) + seq/entropy finalize only.
// ---------------------------------------------------------------------------
__global__ __launch_bounds__(256, 2) void step_kernel(
    const float* __restrict__ emb_table,
    const float* __restrict__ W_ih, const float* __restrict__ W_hh,
    const float* __restrict__ b_ih, const float* __restrict__ b_hh,
    const float* __restrict__ hidden_in,
    const float* __restrict__ Wout, const float* __restrict__ bout,
    const float* __restrict__ gumbels,
    float* __restrict__ pm, float* __restrict__ pS, float* __restrict__ pT,
    float* __restrict__ pbv, int* __restrict__ pbi,
    float* __restrict__ h_ws, float* __restrict__ c_ws,
    int* __restrict__ tok_ws, float* __restrict__ entc_ws,
    float* __restrict__ out, int step)
{
    __shared__ float wV[256][64];   // W_out chunk (logits) / aliased gates[16][256]
    __shared__ float X[16][132];    // [row][emb 0..63 | h 64..127]
    __shared__ int   tokL[16];
    __shared__ float entF[16];

    const bool fin = (step == 16);
    const int t  = threadIdx.x;
    const int rg = fin ? (int)blockIdx.x : ((int)blockIdx.x >> 3);
    const int vs = fin ? 0 : ((int)blockIdx.x & 7);
    const int rowBase = rg * 16;
    const int tv = t & 63;            // lane
    const int tr = t >> 6;            // wave id = row-quad
    const int r0 = tr * 4;

    const int wp   = step & 1;        // write parity
    const int rpar = (step - 1) & 1;  // read parity (valid for step>=1)

    // wV staging geometry (XOR chunk-swizzle, R1-proven)
    const int srow = t >> 4;                 // 0..15
    const int scc  = t & 15;                 // source 16B chunk
    const int sdst = ((scc ^ srow) << 2);    // swizzled column (floats)

    // ---- early, independent: zero-fill one-hot slab step+1 (and slab 0 @D0)
    if (!fin) {
        const f32x4 z = {0.f, 0.f, 0.f, 0.f};
        const size_t col = (size_t)(vs * 1024 + t * 4);
#pragma unroll
        for (int r = 0; r < 16; ++r) {
            const size_t base = (size_t)(rowBase + r) * (17 * 8192);
            __builtin_nontemporal_store(z,
                (f32x4*)(out + base + (size_t)(step + 1) * 8192 + col));
            if (step == 0)
                __builtin_nontemporal_store(z, (f32x4*)(out + base + col));
        }
        if (step == 0 && blockIdx.x == 0 && t == 0) out[ENT_OFF] = 0.f;
    }

    // ---- combine step-1 partials -> token (redundant per block) -------------
    if (step >= 1) {
        if (t < 16) {
            const int row = rowBase + t;
            float m2 = -INFINITY, S2 = 0.f, T2 = 0.f, bv2 = -INFINITY; int bi2 = 0;
            for (int s = 0; s < 8; ++s) {   // ascending split = ascending v
                const int o = rpar * 8192 + s * 1024 + row;
                const float ms = pm[o], Ss = pS[o], Ts = pT[o], bvs = pbv[o];
                const int bis = pbi[o];
                const float mn = fmaxf(m2, ms);
                const float ea = __expf(m2 - mn), eb = __expf(ms - mn);
                S2 = S2 * ea + Ss * eb; T2 = T2 * ea + Ts * eb; m2 = mn;
                if (bvs > bv2 || (bvs == bv2 && bis < bi2)) { bv2 = bvs; bi2 = bis; }
            }
            const float lse  = m2 + logf(S2);
            const float entc = lse - T2 / S2;
            const int tok = bi2;
            if (vs == 0) {
                out[ONEHOT_OFF + (size_t)row * (17 * 8192) + (size_t)step * 8192 + tok] = 1.0f;
                tok_ws[(step - 1) * 1024 + row] = tok;
                entc_ws[(step - 1) * 1024 + row] = entc;
            }
            tokL[t] = tok;
            if (fin) {
                // reconstruct running entropy / seq in R1's serial step order
                float ev = entc_ws[0 * 1024 + row];
                for (int s = 1; s < 15; ++s) ev += entc_ws[s * 1024 + row];
                ev += entc;
                int sl = L_ + 1;
                for (int s = 0; s < 15; ++s) {
                    const int tk = tok_ws[s * 1024 + row];
                    if (tk == EOS && sl == (L_ + 1)) sl = s + 2;
                }
                if (tok == EOS && sl == (L_ + 1)) sl = 15 + 2;   // ==17, no-op (matches ref)
                out[SEQ_OFF + row] = (float)sl;
                entF[t] = ev;
            }
        }
    } else {
        if (t < 16) tokL[t] = SOS;
    }
    __syncthreads();

    if (step == 0 && vs == 0 && t < 16)   // SOS one-hot (after slab-0 zero + sync)
        out[ONEHOT_OFF + (size_t)(rowBase + t) * (17 * 8192) + SOS] = 1.0f;

    if (fin) {
        if (t < 4) {   // 4-row-group sums, same addends as R3 (passed)
            const float a = entF[4 * t] + entF[4 * t + 1] + entF[4 * t + 2] + entF[4 * t + 3];
            atomicAdd(out + ENT_OFF, a * (1.0f / (1024.0f * 16.0f)));
        }
        return;
    }

    // ---- stage X = [emb(tok) | h_prev]; embeds output (vs==0) ---------------
    {
        const int r = t >> 4, k0 = (t & 15) * 4;
        const int row = rowBase + r;
        const int tk = tokL[r];
        float4 evv = *(const float4*)(emb_table + (size_t)tk * 64 + k0);
        *(float4*)&X[r][k0] = evv;
        if (vs == 0) {
            const size_t eo = EMB_OFF + ((size_t)row * 16 + (size_t)step) * 64 + k0;
            out[eo + 0] = evv.x; out[eo + 1] = evv.y; out[eo + 2] = evv.z; out[eo + 3] = evv.w;
        }
        const float* hsrc = (step == 0) ? (hidden_in + (size_t)row * 64 + k0)
                                        : (h_ws + (size_t)rpar * 65536 + (size_t)row * 64 + k0);
        float4 hv = *(const float4*)hsrc;
        *(float4*)&X[r][64 + k0] = hv;
    }
    __syncthreads();

    // ---- gates GEMM: thread t = gate-unit u, 16 rows, K=128 (exact R1 order)
    {
        float* gw = &wV[0][0];               // alias: gates[16][256]
        const int u = t;
        const float bia = b_ih[u] + b_hh[u];
        float acc[16];
#pragma unroll
        for (int r = 0; r < 16; ++r) acc[r] = bia;
        const float* wih = W_ih + (size_t)u * 64;
        const float* whh = W_hh + (size_t)u * 64;
        for (int k4 = 0; k4 < 16; ++k4) {
            const float4 w4 = *(const float4*)(wih + k4 * 4);
#pragma unroll
            for (int r = 0; r < 16; ++r) {
                const float4 x4 = *(const float4*)&X[r][k4 * 4];
                acc[r] += x4.x * w4.x + x4.y * w4.y + x4.z * w4.z + x4.w * w4.w;
            }
        }
        for (int k4 = 0; k4 < 16; ++k4) {
            const float4 w4 = *(const float4*)(whh + k4 * 4);
#pragma unroll
            for (int r = 0; r < 16; ++r) {
                const float4 x4 = *(const float4*)&X[r][64 + k4 * 4];
                acc[r] += x4.x * w4.x + x4.y * w4.y + x4.z * w4.z + x4.w * w4.w;
            }
        }
#pragma unroll
        for (int r = 0; r < 16; ++r) gw[r * 256 + u] = acc[r];
    }
    __syncthreads();

    // ---- LSTM cell: 16 rows x 64 units, 4 per thread (exact R1 math) --------
    {
        const float* gw = &wV[0][0];
#pragma unroll
        for (int q = 0; q < 4; ++q) {
            const int lin = q * 256 + t;
            const int r = lin >> 6, uu = lin & 63;
            const int row = rowBase + r;
            const float ii = gw[r * 256 + uu];
            const float ff = gw[r * 256 + 64 + uu];
            const float gg = gw[r * 256 + 128 + uu];
            const float oo = gw[r * 256 + 192 + uu];
            const float cp = (step == 0) ? 0.f
                           : c_ws[(size_t)rpar * 65536 + (size_t)row * 64 + uu];
            const float si = 1.f / (1.f + expf(-ii));
            const float sf = 1.f / (1.f + expf(-ff));
            const float so = 1.f / (1.f + expf(-oo));
            const float cn = sf * cp + si * tanhf(gg);
            const float hn = so * tanhf(cn);
            X[r][64 + uu] = hn;
            if (vs == 0) {
                c_ws[(size_t)wp * 65536 + (size_t)row * 64 + uu] = cn;
                h_ws[(size_t)wp * 65536 + (size_t)row * 64 + uu] = hn;
            }
        }
    }
    __syncthreads();

    // ---- logits slice (R1-proven): 4 chunks of 256 v --------------------------
    const float* gstep = gumbels + (size_t)step * 8388608ull;   // step*B*V

    float m[4], S[4], T[4], bv[4];
    int   bi[4];
#pragma unroll
    for (int r = 0; r < 4; ++r) {
        m[r] = -INFINITY; S[r] = 0.f; T[r] = 0.f; bv[r] = -INFINITY; bi[r] = 0;
    }

    for (int cc = 0; cc < 4; ++cc) {
        const int vglob = vs * 1024 + cc * 256;

        float gv[16], bo[4];
#pragma unroll
        for (int j = 0; j < 4; ++j) {
            const int v = vglob + 64 * j + tv;
            bo[j] = bout[v];
#pragma unroll
            for (int r = 0; r < 4; ++r)
                gv[j * 4 + r] = gstep[(size_t)(rowBase + r0 + r) * V_ + v];
        }

        __syncthreads();   // previous chunk's compute (and gates alias) done
#pragma unroll
        for (int j = 0; j < 16; ++j) {           // stage 256x64 W_out chunk
            const int vl = srow + 16 * j;
            float4 w = *(const float4*)(Wout + (size_t)(vglob + vl) * 64 + scc * 4);
            *(float4*)&wV[vl][sdst] = w;
        }
        __syncthreads();

        float acc[4][4];
#pragma unroll
        for (int r = 0; r < 4; ++r)
#pragma unroll
            for (int j = 0; j < 4; ++j) acc[r][j] = 0.f;

#pragma unroll 4
        for (int k4 = 0; k4 < 16; ++k4) {
            const int ks = ((k4 ^ (tv & 15)) << 2);   // swizzled column
            float4 wv[4], hv[4];
#pragma unroll
            for (int j = 0; j < 4; ++j) wv[j] = *(const float4*)&wV[tv + 64 * j][ks];
#pragma unroll
            for (int r = 0; r < 4; ++r) hv[r] = *(const float4*)&X[r0 + r][64 + k4 * 4];
#pragma unroll
            for (int r = 0; r < 4; ++r)
#pragma unroll
                for (int j = 0; j < 4; ++j)
                    acc[r][j] += hv[r].x * wv[j].x + hv[r].y * wv[j].y +
                                 hv[r].z * wv[j].z + hv[r].w * wv[j].w;
        }

        // epilogue: logits -> online stats + argmax(l+g). v ascending in j.
#pragma unroll
        for (int j = 0; j < 4; ++j) {
            const int v  = vglob + 64 * j + tv;
#pragma unroll
            for (int r = 0; r < 4; ++r) {
                const float l = acc[r][j] + bo[j];
                const float s = l + gv[j * 4 + r];
                if (s > bv[r]) { bv[r] = s; bi[r] = v; }   // strict > keeps lowest v
                const float mn = fmaxf(m[r], l);
                const float e  = __expf(-fabsf(l - m[r])); // exp(-inf)=0 first time
                const bool nw  = l > m[r];
                const float a  = nw ? e : 1.f;
                const float b2 = nw ? 1.f : e;
                S[r] = S[r] * a + b2;
                T[r] = T[r] * a + l * b2;
                m[r] = mn;
            }
        }
    }

    // wave-64 butterfly reduction across lanes (each wave = 4 rows)
#pragma unroll
    for (int off = 1; off < 64; off <<= 1) {
#pragma unroll
        for (int r = 0; r < 4; ++r) {
            const float mo  = __shfl_xor(m[r], off);
            const float So  = __shfl_xor(S[r], off);
            const float To  = __shfl_xor(T[r], off);
            const float bvo = __shfl_xor(bv[r], off);
            const int   bio = __shfl_xor(bi[r], off);
            const float mn = fmaxf(m[r], mo);
            const float ea = __expf(m[r] - mn);
            const float eb = __expf(mo - mn);
            S[r] = S[r] * ea + So * eb;
            T[r] = T[r] * ea + To * eb;
            m[r] = mn;
            if (bvo > bv[r] || (bvo == bv[r] && bio < bi[r])) { bv[r] = bvo; bi[r] = bio; }
        }
    }
    if (tv == 0) {
#pragma unroll
        for (int r = 0; r < 4; ++r) {
            const int row = rowBase + r0 + r;
            const int o = wp * 8192 + vs * 1024 + row;
            pm[o] = m[r]; pS[o] = S[r]; pT[o] = T[r]; pbv[o] = bv[r]; pbi[o] = bi[r];
        }
    }
}

extern "C" void kernel_launch(void* const* d_in, const int* in_sizes, int n_in,
                              void* d_out, int out_size, void* d_ws, size_t ws_size,
                              hipStream_t stream) {
    (void)in_sizes; (void)ws_size; (void)out_size;
    if (n_in < 9) return;
    const float* hidden    = (const float*)d_in[0];
    const float* embedding = (const float*)d_in[1];
    const float* W_ih      = (const float*)d_in[2];
    const float* W_hh      = (const float*)d_in[3];
    const float* b_ih      = (const float*)d_in[4];
    const float* b_hh      = (const float*)d_in[5];
    const float* W_out     = (const float*)d_in[6];
    const float* b_out     = (const float*)d_in[7];
    const float* gumbels   = (const float*)d_in[8];
    float* out = (float*)d_out;

    // workspace (floats): pm/pS/pT/pbv/pbi [2][8192] each | h_ws [2][65536] |
    // c_ws [2][65536] | tok_ws [16][1024] int | entc_ws [16][1024]
    float* wsf = (float*)d_ws;
    float* pm   = wsf;
    float* pS   = wsf + 16384;
    float* pT   = wsf + 32768;
    float* pbv  = wsf + 49152;
    int*   pbi  = (int*)(wsf + 65536);
    float* h_ws = wsf + 81920;
    float* c_ws = wsf + 212992;
    int*   tok_ws  = (int*)(wsf + 344064);
    float* entc_ws = wsf + 360448;

    (void)hipMemcpyAsync(out + HID_OFF, hidden, (size_t)B_ * H_ * sizeof(float),
                         hipMemcpyDeviceToDevice, stream);
    for (int i = 0; i < 16; ++i) {
        step_kernel<<<512, 256, 0, stream>>>(embedding, W_ih, W_hh, b_ih, b_hh,
            hidden, W_out, b_out, gumbels, pm, pS, pT, pbv, pbi,
            h_ws, c_ws, tok_ws, entc_ws, out, i);
    }
    step_kernel<<<64, 256, 0, stream>>>(embedding, W_ih, W_hh, b_ih, b_hh,
        hidden, W_out, b_out, gumbels, pm, pS, pT, pbv, pbi,
        h_ws, c_ws, tok_ws, entc_ws, out, 16);
}